// Round 5
// baseline (71.114 us; speedup 1.0000x reference)
//
#include <hip/hip_runtime.h>

// MixedActivation: x[1000000][48] fp32. Column c: (c%6)<3 -> x*x,
// else PReLU with slope prelu_a[(c%6)-3].
// Streaming op, 384 MB HBM traffic, memory-bound.
// R5: unroll-4 with grouped loads-then-stores (longer same-direction HBM
// bursts, fewer read/write turnarounds) + loop-invariant pattern key
// (stride % 3 == 0) + nontemporal hints (R3: +9%).

typedef float floatv4 __attribute__((ext_vector_type(4)));

__global__ __launch_bounds__(256)
void MixedActivation_kernel(const floatv4* __restrict__ x,
                            const float* __restrict__ a,
                            floatv4* __restrict__ out,
                            int n4) {
    const float a0 = a[0], a1 = a[1], a2 = a[2];
    const int stride = gridDim.x * blockDim.x;   // launcher guarantees %3==0
    int i = blockIdx.x * blockDim.x + threadIdx.x;

    // Pattern key constant across iterations (stride % 3 == 0).
    // (4*i) % 6: i%3 = 0,1,2 -> base 0,4,2.
    const int t = i % 3;
    const int b = (t == 0) ? 0 : (t == 1) ? 4 : 2;

    float slope[4];
    bool  issq[4];
#pragma unroll
    for (int k = 0; k < 4; ++k) {
        int m = b + k;
        if (m >= 6) m -= 6;
        slope[k] = (m == 3) ? a0 : (m == 4) ? a1 : a2;
        issq[k]  = (m < 3);
    }

    // Main: 4 loads issued together, then 4 stores — long same-direction
    // bursts at the memory controller.
    for (; i + 3 * stride < n4; i += 4 * stride) {
        floatv4 v0 = __builtin_nontemporal_load(&x[i]);
        floatv4 v1 = __builtin_nontemporal_load(&x[i + stride]);
        floatv4 v2 = __builtin_nontemporal_load(&x[i + 2 * stride]);
        floatv4 v3 = __builtin_nontemporal_load(&x[i + 3 * stride]);
        floatv4 r0, r1, r2, r3;
#pragma unroll
        for (int k = 0; k < 4; ++k) {
            const float p0 = fmaxf(v0[k], 0.0f) + slope[k] * fminf(v0[k], 0.0f);
            const float p1 = fmaxf(v1[k], 0.0f) + slope[k] * fminf(v1[k], 0.0f);
            const float p2 = fmaxf(v2[k], 0.0f) + slope[k] * fminf(v2[k], 0.0f);
            const float p3 = fmaxf(v3[k], 0.0f) + slope[k] * fminf(v3[k], 0.0f);
            r0[k] = issq[k] ? v0[k] * v0[k] : p0;
            r1[k] = issq[k] ? v1[k] * v1[k] : p1;
            r2[k] = issq[k] ? v2[k] * v2[k] : p2;
            r3[k] = issq[k] ? v3[k] * v3[k] : p3;
        }
        __builtin_nontemporal_store(r0, &out[i]);
        __builtin_nontemporal_store(r1, &out[i + stride]);
        __builtin_nontemporal_store(r2, &out[i + 2 * stride]);
        __builtin_nontemporal_store(r3, &out[i + 3 * stride]);
    }
    // Tail: up to 3 remaining strided elements per thread.
    for (; i < n4; i += stride) {
        floatv4 v = __builtin_nontemporal_load(&x[i]);
        floatv4 r;
#pragma unroll
        for (int k = 0; k < 4; ++k) {
            const float p = fmaxf(v[k], 0.0f) + slope[k] * fminf(v[k], 0.0f);
            r[k] = issq[k] ? v[k] * v[k] : p;
        }
        __builtin_nontemporal_store(r, &out[i]);
    }
}

extern "C" void kernel_launch(void* const* d_in, const int* in_sizes, int n_in,
                              void* d_out, int out_size, void* d_ws, size_t ws_size,
                              hipStream_t stream) {
    const float* x = (const float*)d_in[0];
    const float* a = (const float*)d_in[1];
    float* out = (float*)d_out;

    const int n = out_size;        // 48,000,000 elements
    const int n4 = n / 4;          // 12,000,000 float4s

    const int block = 256;
    // 2046 blocks: stride = 523776 float4s, divisible by 3 (pattern key
    // loop-invariant) and ~8 blocks/CU (full occupancy).
    const int grid = 2046;

    MixedActivation_kernel<<<grid, block, 0, stream>>>(
        (const floatv4*)x, a, (floatv4*)out, n4);
}

// Round 6
// 61.610 us; speedup vs baseline: 1.1543x; 1.1543x over previous
//
#include <hip/hip_runtime.h>

// MixedActivation: x[1000000][48] fp32. Column c: (c%6)<3 -> x*x,
// else PReLU with slope prelu_a[(c%6)-3].
// Streaming op, 384 MB HBM traffic, memory-bound.
// R6: flat launch — exactly one float4 per thread (12,000,000 = 46875*256,
// no remainder, no loop, no bounds check). Nontemporal hints kept (R3: +9%).

typedef float floatv4 __attribute__((ext_vector_type(4)));

__global__ __launch_bounds__(256)
void MixedActivation_kernel(const floatv4* __restrict__ x,
                            const float* __restrict__ a,
                            floatv4* __restrict__ out) {
    const int i = blockIdx.x * blockDim.x + threadIdx.x;

    floatv4 v = __builtin_nontemporal_load(&x[i]);

    // col of elem k is (4i + k); (4i)%6 depends only on i%3: 0,1,2 -> 0,4,2.
    const int t = i % 3;
    const int b = (t == 0) ? 0 : (t == 1) ? 4 : 2;
    const float a0 = a[0], a1 = a[1], a2 = a[2];

    floatv4 r;
#pragma unroll
    for (int k = 0; k < 4; ++k) {
        int m = b + k;
        if (m >= 6) m -= 6;
        const float val = v[k];
        const float slope = (m == 3) ? a0 : (m == 4) ? a1 : a2;
        const float pr = fmaxf(val, 0.0f) + slope * fminf(val, 0.0f);
        r[k] = (m < 3) ? val * val : pr;
    }
    __builtin_nontemporal_store(r, &out[i]);
}

extern "C" void kernel_launch(void* const* d_in, const int* in_sizes, int n_in,
                              void* d_out, int out_size, void* d_ws, size_t ws_size,
                              hipStream_t stream) {
    const float* x = (const float*)d_in[0];
    const float* a = (const float*)d_in[1];
    float* out = (float*)d_out;

    const int n = out_size;        // 48,000,000 elements
    const int n4 = n / 4;          // 12,000,000 float4s
    const int block = 256;
    const int grid = n4 / block;   // 46875 exactly, no remainder

    MixedActivation_kernel<<<grid, block, 0, stream>>>(
        (const floatv4*)x, a, (floatv4*)out);
}